// Round 3
// baseline (21.153 us; speedup 1.0000x reference)
//
#include <hip/hip_runtime.h>

#define HIDDEN 768
#define LN_EPS 1e-5f

typedef float f32x4 __attribute__((ext_vector_type(4)));

// Two adjacent token rows per 64-lane wave. Each lane handles 3 float4
// (12 floats) per row at float4 index = lane + k*64, k in 0..2 (coalesced).
// 18 independent gather loads issue up front for max memory-level
// parallelism; the two shuffle-reduce chains interleave; stores are
// nontemporal (streaming, never re-read).
__global__ __launch_bounds__(256) void bert_embedding_kernel(
    const int* __restrict__ input_ids,
    const int* __restrict__ token_type_ids,
    const float* __restrict__ tok_w,
    const float* __restrict__ pos_w,
    const float* __restrict__ type_w,
    const float* __restrict__ gamma,
    const float* __restrict__ beta,
    float* __restrict__ out,
    int n_rows, int S)
{
    const int pair = (blockIdx.x * blockDim.x + threadIdx.x) >> 6;
    const int lane = threadIdx.x & 63;
    const int row0 = pair * 2;
    if (row0 >= n_rows) return;
    const int row1 = row0 + 1;

    const int tok0 = input_ids[row0];
    const int tok1 = input_ids[row1];
    const int typ0 = token_type_ids[row0];
    const int typ1 = token_type_ids[row1];
    const int s0 = row0 % S;
    const int s1 = row1 % S;

    const f32x4* __restrict__ tw0 = reinterpret_cast<const f32x4*>(tok_w  + (size_t)tok0 * HIDDEN);
    const f32x4* __restrict__ tw1 = reinterpret_cast<const f32x4*>(tok_w  + (size_t)tok1 * HIDDEN);
    const f32x4* __restrict__ pw0 = reinterpret_cast<const f32x4*>(pos_w  + (size_t)s0   * HIDDEN);
    const f32x4* __restrict__ pw1 = reinterpret_cast<const f32x4*>(pos_w  + (size_t)s1   * HIDDEN);
    const f32x4* __restrict__ yw0 = reinterpret_cast<const f32x4*>(type_w + (size_t)typ0 * HIDDEN);
    const f32x4* __restrict__ yw1 = reinterpret_cast<const f32x4*>(type_w + (size_t)typ1 * HIDDEN);
    const f32x4* __restrict__ g4  = reinterpret_cast<const f32x4*>(gamma);
    const f32x4* __restrict__ b4  = reinterpret_cast<const f32x4*>(beta);

    // Issue every load before any dependent arithmetic.
    f32x4 a0[3], p0[3], c0[3], a1[3], p1[3], c1[3], g[3], bb[3];
    #pragma unroll
    for (int k = 0; k < 3; ++k) {
        const int idx = lane + k * 64;
        a0[k] = tw0[idx];  p0[k] = pw0[idx];  c0[k] = yw0[idx];
        a1[k] = tw1[idx];  p1[k] = pw1[idx];  c1[k] = yw1[idx];
        g[k]  = g4[idx];   bb[k] = b4[idx];
    }

    f32x4 e0[3], e1[3];
    float sum0 = 0.f, sq0 = 0.f, sum1 = 0.f, sq1 = 0.f;
    #pragma unroll
    for (int k = 0; k < 3; ++k) {
        const f32x4 v0 = a0[k] + p0[k] + c0[k];
        const f32x4 v1 = a1[k] + p1[k] + c1[k];
        e0[k] = v0;  e1[k] = v1;
        sum0 += v0.x + v0.y + v0.z + v0.w;
        sq0  += v0.x * v0.x + v0.y * v0.y + v0.z * v0.z + v0.w * v0.w;
        sum1 += v1.x + v1.y + v1.z + v1.w;
        sq1  += v1.x * v1.x + v1.y * v1.y + v1.z * v1.z + v1.w * v1.w;
    }

    // Interleaved wave-wide butterfly reductions (independent chains).
    #pragma unroll
    for (int m = 1; m < 64; m <<= 1) {
        sum0 += __shfl_xor(sum0, m);
        sum1 += __shfl_xor(sum1, m);
        sq0  += __shfl_xor(sq0, m);
        sq1  += __shfl_xor(sq1, m);
    }

    const float inv_h = 1.0f / (float)HIDDEN;
    const float mean0 = sum0 * inv_h;
    const float mean1 = sum1 * inv_h;
    const float rs0 = rsqrtf(sq0 * inv_h - mean0 * mean0 + LN_EPS);
    const float rs1 = rsqrtf(sq1 * inv_h - mean1 * mean1 + LN_EPS);

    f32x4* __restrict__ o0 = reinterpret_cast<f32x4*>(out + (size_t)row0 * HIDDEN);
    f32x4* __restrict__ o1 = reinterpret_cast<f32x4*>(out + (size_t)row1 * HIDDEN);

    #pragma unroll
    for (int k = 0; k < 3; ++k) {
        const int idx = lane + k * 64;
        f32x4 r0, r1;
        r0.x = (e0[k].x - mean0) * rs0 * g[k].x + bb[k].x;
        r0.y = (e0[k].y - mean0) * rs0 * g[k].y + bb[k].y;
        r0.z = (e0[k].z - mean0) * rs0 * g[k].z + bb[k].z;
        r0.w = (e0[k].w - mean0) * rs0 * g[k].w + bb[k].w;
        r1.x = (e1[k].x - mean1) * rs1 * g[k].x + bb[k].x;
        r1.y = (e1[k].y - mean1) * rs1 * g[k].y + bb[k].y;
        r1.z = (e1[k].z - mean1) * rs1 * g[k].z + bb[k].z;
        r1.w = (e1[k].w - mean1) * rs1 * g[k].w + bb[k].w;
        __builtin_nontemporal_store(r0, &o0[idx]);
        __builtin_nontemporal_store(r1, &o1[idx]);
    }
}

extern "C" void kernel_launch(void* const* d_in, const int* in_sizes, int n_in,
                              void* d_out, int out_size, void* d_ws, size_t ws_size,
                              hipStream_t stream) {
    const int*   input_ids      = (const int*)d_in[0];
    const int*   token_type_ids = (const int*)d_in[1];
    const float* tok_w          = (const float*)d_in[2];
    const float* pos_w          = (const float*)d_in[3];
    const float* type_w         = (const float*)d_in[4];
    const float* gamma          = (const float*)d_in[5];
    const float* beta           = (const float*)d_in[6];
    float* out = (float*)d_out;

    const int n_rows = in_sizes[0];          // B * S = 16384
    const int S = in_sizes[3] / HIDDEN;      // pos_w rows = 512

    const int n_pairs = (n_rows + 1) / 2;    // 8192 waves
    const int waves_per_block = 4;           // 256 threads
    const int blocks = (n_pairs + waves_per_block - 1) / waves_per_block;
    bert_embedding_kernel<<<blocks, 256, 0, stream>>>(
        input_ids, token_type_ids, tok_w, pos_w, type_w, gamma, beta,
        out, n_rows, S);
}